// Round 3
// baseline (1714.775 us; speedup 1.0000x reference)
//
#include <hip/hip_runtime.h>
#include <hip/hip_bf16.h>

typedef __hip_bfloat16 bf16;
typedef float f32x4 __attribute__((ext_vector_type(4)));
typedef short s16x8 __attribute__((ext_vector_type(8)));
typedef int i32x4 __attribute__((ext_vector_type(4)));

#define S_LEN 1024
#define BATCH 2
#define TDIM 138
#define DMOD 1024
#define NHEAD 16
#define DHEAD 64
#define NLAYER 8
#define FDIM 2048
#define MROWS 2048
static const size_t DD_ = (size_t)DMOD * DMOD;   // 1M elems
static const size_t FD_ = (size_t)FDIM * DMOD;   // 2M elems

__device__ __forceinline__ void load_lds16(const bf16* g, bf16* l) {
  __builtin_amdgcn_global_load_lds((const __attribute__((address_space(1))) void*)g,
                                   (__attribute__((address_space(3))) void*)l, 16, 0, 0);
}

__device__ __forceinline__ unsigned pack2(float a, float b) {
  unsigned x = __builtin_bit_cast(unsigned short, __float2bfloat16(a));
  unsigned y = __builtin_bit_cast(unsigned short, __float2bfloat16(b));
  return x | (y << 16);
}

// ---------------- per-layer weight f32 -> bf16 convert (one dispatch) ----------------
__global__ __launch_bounds__(256) void f2b_layer(
    const float4* __restrict__ Wq, const float4* __restrict__ Wk,
    const float4* __restrict__ Wv, const float4* __restrict__ Wo,
    const float4* __restrict__ W1, const float4* __restrict__ W2,
    ushort4* __restrict__ dst) {
  int i = blockIdx.x * 256 + threadIdx.x;
  const int DD4 = (int)(DD_ / 4), FD4 = (int)(FD_ / 4);
  if (i >= 4 * DD4 + 2 * FD4) return;
  const float4* src; int off;
  if (i < 3 * DD4) { int w = i / DD4; off = i - w * DD4; src = w == 0 ? Wq : (w == 1 ? Wk : Wv); }
  else if (i < 4 * DD4) { src = Wo; off = i - 3 * DD4; }
  else if (i < 4 * DD4 + FD4) { src = W1; off = i - 4 * DD4; }
  else { src = W2; off = i - 4 * DD4 - FD4; }
  float4 v = src[off];
  ushort4 o;
  o.x = __builtin_bit_cast(unsigned short, __float2bfloat16(v.x));
  o.y = __builtin_bit_cast(unsigned short, __float2bfloat16(v.y));
  o.z = __builtin_bit_cast(unsigned short, __float2bfloat16(v.z));
  o.w = __builtin_bit_cast(unsigned short, __float2bfloat16(v.w));
  dst[i] = o;
}

// ---------------- rope table ----------------
__global__ __launch_bounds__(256) void rope_table(float2* __restrict__ t) {
  int idx = blockIdx.x * 256 + threadIdx.x;
  if (idx >= S_LEN * 32) return;
  int s = idx >> 5, i = idx & 31;
  float freq = __expf(-(float)i * (2.0f / (float)DHEAD) * 9.210340371976184f);
  float sn, cs;
  sincosf((float)s * freq, &sn, &cs);
  t[idx] = make_float2(cs, sn);
}

// ---------------- Win transpose ----------------
__global__ __launch_bounds__(256) void transpose_win(const float* __restrict__ Win,
                                                     float* __restrict__ WinT) {
  int i = blockIdx.x * 256 + threadIdx.x;
  if (i >= TDIM * DMOD) return;
  int t = i / DMOD, d = i % DMOD;
  WinT[i] = Win[d * TDIM + t];
}

// ---------------- embed ----------------
__global__ __launch_bounds__(256) void embed_kernel(const float* __restrict__ tokens,
    const float* __restrict__ WinT, const float* __restrict__ binp,
    const float* __restrict__ pos, float* __restrict__ xf, bf16* __restrict__ xb) {
  int m = blockIdx.x;
  int d = blockIdx.y * 256 + threadIdx.x;
  int s = m >> 1;
  __shared__ float tok[TDIM];
  if (threadIdx.x < TDIM) tok[threadIdx.x] = tokens[m * TDIM + threadIdx.x];
  __syncthreads();
  float acc = binp[d] + pos[s * DMOD + d];
  for (int t = 0; t < TDIM; t++) acc += tok[t] * WinT[t * DMOD + d];
  xf[(size_t)m * DMOD + d] = acc;
  xb[(size_t)m * DMOD + d] = __float2bfloat16(acc);
}

// ---------------- 128-tile NT GEMM (m97 structure) ----------------
template<int TN, int EPI>
__global__ __launch_bounds__(256) void gemm128(
    const bf16* __restrict__ A, const bf16* __restrict__ W,
    const float* __restrict__ b0p, const float* __restrict__ b1p, const float* __restrict__ b2p,
    const float2* __restrict__ rope2, float* __restrict__ Cf,
    bf16* __restrict__ Cb0, bf16* __restrict__ Cb1, bf16* __restrict__ Cb2,
    int N, int K) {
  constexpr int NJ = TN / 32;
  __shared__ bf16 As[128 * 32];
  __shared__ bf16 Bs[TN * 32];
  int bn = blockIdx.x * TN, bm = blockIdx.y * 128;
  int tid = threadIdx.x, lane = tid & 63, w = tid >> 6;
  int lo = lane & 15, hi = lane >> 4;
  int wr = (w >> 1) * 64, wc = (w & 1) * (TN / 2);
  f32x4 acc[4][NJ] = {};

  int srow = tid >> 2, sseg = tid & 3;
  const bf16* gA = A + (size_t)(bm + srow) * K + sseg * 8;
  const bf16* gB = W + (size_t)(bn + srow) * K + sseg * 8;
  bf16* lA = As + srow * 32 + sseg * 8;
  bf16* lB = Bs + srow * 32 + sseg * 8;

  for (int k0 = 0; k0 < K; k0 += 32) {
    load_lds16(gA + k0, lA);
    load_lds16(gA + (size_t)64 * K + k0, lA + 64 * 32);
    load_lds16(gB + k0, lB);
    if constexpr (TN == 128) load_lds16(gB + (size_t)64 * K + k0, lB + 64 * 32);
    __syncthreads();
    s16x8 af[4], bfr[NJ];
#pragma unroll
    for (int mi = 0; mi < 4; mi++) af[mi] = *(const s16x8*)(As + (wr + mi * 16 + lo) * 32 + hi * 8);
#pragma unroll
    for (int nj = 0; nj < NJ; nj++) bfr[nj] = *(const s16x8*)(Bs + (wc + nj * 16 + lo) * 32 + hi * 8);
#pragma unroll
    for (int mi = 0; mi < 4; mi++)
#pragma unroll
      for (int nj = 0; nj < NJ; nj++)
        acc[mi][nj] = __builtin_amdgcn_mfma_f32_16x16x32_bf16(af[mi], bfr[nj], acc[mi][nj], 0, 0, 0);
    __syncthreads();
  }

#pragma unroll
  for (int mi = 0; mi < 4; mi++)
#pragma unroll
    for (int nj = 0; nj < NJ; nj++)
#pragma unroll
      for (int r = 0; r < 4; r++) {
        int m = bm + wr + mi * 16 + hi * 4 + r;
        int n = bn + wc + nj * 16 + lo;
        float v = acc[mi][nj][r];
        if constexpr (EPI == 0) {
          int which = n >> 10;
          int d = n & 1023, h = d >> 6, dh = d & 63;
          int s = m >> 1, bb = m & 1;
          const float* bp = which == 0 ? b0p : (which == 1 ? b1p : b2p);
          v += bp[d];
          if (which < 2) {
            float pv = __shfl_xor(v, 1);
            float2 cn = rope2[s * 32 + (dh >> 1)];
            float o = (dh & 1) ? (v * cn.x + pv * cn.y) : (v * cn.x - pv * cn.y);
            bf16* dst = which == 0 ? Cb0 : Cb1;
            dst[(((size_t)(bb * NHEAD + h)) * S_LEN + s) * DHEAD + dh] = __float2bfloat16(o);
          } else {
            Cb2[(((size_t)(bb * NHEAD + h)) * DHEAD + dh) * S_LEN + s] = __float2bfloat16(v);
          }
        } else if constexpr (EPI == 1) {
          Cf[(size_t)m * N + n] = v + b0p[n];
        } else {
          Cb0[(size_t)m * N + n] = __float2bfloat16(fmaxf(v + b0p[n], 0.0f));
        }
      }
}

// ---------------- split-K flash attention, part 1 ----------------
// One wave = one (16-q-row tile, 256-key chunk). Swapped QK^T, lane-local softmax
// in exp2 domain, no LDS. Partials: pO f32 [pbase][16][64], pML [pbase][m16|l16].
__global__ __launch_bounds__(256) void flash_part(const bf16* __restrict__ Q,
    const bf16* __restrict__ K, const bf16* __restrict__ Vt,
    float* __restrict__ pO, float* __restrict__ pML) {
  int bh = blockIdx.y;
  int w = threadIdx.x >> 6, lane = threadIdx.x & 63;
  int lo = lane & 15, hi = lane >> 4;
  int widx = blockIdx.x * 4 + w;           // 0..159
  int ch, qt;
  if (widx < 64)       { ch = 0; qt = widx; }
  else if (widx < 112) { ch = 1; qt = 16 + widx - 64; }
  else if (widx < 144) { ch = 2; qt = 32 + widx - 112; }
  else                 { ch = 3; qt = 48 + widx - 144; }
  int q0 = qt * 16, qa = q0 + lo;
  int kc0 = ch * 256;
  int kend = min(kc0 + 256, q0 + 16);
  int nkt = (kend - kc0 + 31) >> 5;

  const size_t qkb = (size_t)bh * S_LEN * DHEAD;
  const bf16* qp = Q + qkb + (size_t)qa * DHEAD + hi * 8;
  s16x8 bq0 = *(const s16x8*)qp;
  s16x8 bq1 = *(const s16x8*)(qp + 32);
  f32x4 accO[4] = {};
  float mv = -INFINITY, lv = 0.0f;
  const float SC = 0.18033688011112042f;   // (1/8) * log2(e)

  for (int kt = 0; kt < nkt; kt++) {
    int kc = kc0 + kt * 32;
    const bf16* kp = K + qkb + (size_t)(kc + lo) * DHEAD + hi * 8;
    s16x8 ka0 = *(const s16x8*)kp;
    s16x8 ka1 = *(const s16x8*)(kp + 32);
    s16x8 ka2 = *(const s16x8*)(kp + 16 * DHEAD);
    s16x8 ka3 = *(const s16x8*)(kp + 16 * DHEAD + 32);
    f32x4 st0 = {}, st1 = {};
    st0 = __builtin_amdgcn_mfma_f32_16x16x32_bf16(ka0, bq0, st0, 0, 0, 0);
    st0 = __builtin_amdgcn_mfma_f32_16x16x32_bf16(ka1, bq1, st0, 0, 0, 0);
    st1 = __builtin_amdgcn_mfma_f32_16x16x32_bf16(ka2, bq0, st1, 0, 0, 0);
    st1 = __builtin_amdgcn_mfma_f32_16x16x32_bf16(ka3, bq1, st1, 0, 0, 0);
    // prefetch V for this tile early (overlaps softmax chain)
    const bf16* vp = Vt + qkb + (size_t)lo * S_LEN + kc + hi * 8;
    s16x8 va0 = *(const s16x8*)(vp);
    s16x8 va1 = *(const s16x8*)(vp + (size_t)16 * S_LEN);
    s16x8 va2 = *(const s16x8*)(vp + (size_t)32 * S_LEN);
    s16x8 va3 = *(const s16x8*)(vp + (size_t)48 * S_LEN);

    float p[8], pmax = -INFINITY;
    if (kc + 31 > q0) {          // diagonal tile: causal mask (wave-uniform branch)
#pragma unroll
      for (int r = 0; r < 4; r++) {
        int k0a = kc + hi * 4 + r;
        float s0 = (k0a <= qa) ? st0[r] * SC : -INFINITY;
        float s1 = (k0a + 16 <= qa) ? st1[r] * SC : -INFINITY;
        p[r] = s0; p[4 + r] = s1;
        pmax = fmaxf(pmax, fmaxf(s0, s1));
      }
    } else {
#pragma unroll
      for (int r = 0; r < 4; r++) {
        float s0 = st0[r] * SC, s1 = st1[r] * SC;
        p[r] = s0; p[4 + r] = s1;
        pmax = fmaxf(pmax, fmaxf(s0, s1));
      }
    }
    pmax = fmaxf(pmax, __shfl_xor(pmax, 16));
    pmax = fmaxf(pmax, __shfl_xor(pmax, 32));
    float mnew = fmaxf(mv, pmax);
    float fs = exp2f(mv - mnew);
    float sum = 0.0f;
#pragma unroll
    for (int j = 0; j < 8; j++) { p[j] = exp2f(p[j] - mnew); sum += p[j]; }
    sum += __shfl_xor(sum, 16);
    sum += __shfl_xor(sum, 32);
    lv = lv * fs + sum;
    mv = mnew;
#pragma unroll
    for (int c = 0; c < 4; c++) accO[c] *= fs;
    // redistribute P -> PV B-frag: lane needs P[q=lo][k=hi*8..hi*8+7]
    unsigned u0 = pack2(p[0], p[1]), u1 = pack2(p[2], p[3]);
    unsigned u2 = pack2(p[4], p[5]), u3 = pack2(p[6], p[7]);
    int s1l = lo + ((hi & 1) << 5);
    int s2l = s1l + 16;
    unsigned a0 = (unsigned)__shfl((int)u0, s1l), a1 = (unsigned)__shfl((int)u1, s1l);
    unsigned a2 = (unsigned)__shfl((int)u0, s2l), a3 = (unsigned)__shfl((int)u1, s2l);
    unsigned c0 = (unsigned)__shfl((int)u2, s1l), c1 = (unsigned)__shfl((int)u3, s1l);
    unsigned c2 = (unsigned)__shfl((int)u2, s2l), c3 = (unsigned)__shfl((int)u3, s2l);
    bool lk = hi < 2;
    i32x4 pi;
    pi.x = (int)(lk ? a0 : c0); pi.y = (int)(lk ? a1 : c1);
    pi.z = (int)(lk ? a2 : c2); pi.w = (int)(lk ? a3 : c3);
    s16x8 pf = __builtin_bit_cast(s16x8, pi);
    accO[0] = __builtin_amdgcn_mfma_f32_16x16x32_bf16(va0, pf, accO[0], 0, 0, 0);
    accO[1] = __builtin_amdgcn_mfma_f32_16x16x32_bf16(va1, pf, accO[1], 0, 0, 0);
    accO[2] = __builtin_amdgcn_mfma_f32_16x16x32_bf16(va2, pf, accO[2], 0, 0, 0);
    accO[3] = __builtin_amdgcn_mfma_f32_16x16x32_bf16(va3, pf, accO[3], 0, 0, 0);
  }

  int pbase = (bh * 64 + qt) * 4 + ch;
  float* po = pO + (size_t)pbase * 1024 + lo * 64 + hi * 4;
#pragma unroll
  for (int c = 0; c < 4; c++) *(f32x4*)(po + c * 16) = accO[c];
  if (hi == 0) {
    pML[pbase * 32 + lo] = mv;
    pML[pbase * 32 + 16 + lo] = lv;
  }
}

// ---------------- split-K flash attention, merge ----------------
__global__ __launch_bounds__(256) void flash_merge(const float* __restrict__ pO,
    const float* __restrict__ pML, bf16* __restrict__ O) {
  int qt = blockIdx.x, bh = blockIdx.y;
  int b = bh >> 4, h = bh & 15;
  int nch = (qt >> 4) + 1;
  int t = threadIdx.x;
  int dh = t & 63, r0 = t >> 6;
  int pb0 = (bh * 64 + qt) * 4;
#pragma unroll
  for (int j = 0; j < 4; j++) {
    int row = r0 + j * 4;
    float ms = -INFINITY;
    for (int i = 0; i < nch; i++) ms = fmaxf(ms, pML[(pb0 + i) * 32 + row]);
    float l = 0.0f, o = 0.0f;
    for (int i = 0; i < nch; i++) {
      float wgt = exp2f(pML[(pb0 + i) * 32 + row] - ms);
      l += wgt * pML[(pb0 + i) * 32 + 16 + row];
      o += wgt * pO[(size_t)(pb0 + i) * 1024 + row * 64 + dh];
    }
    int q = qt * 16 + row;
    O[((size_t)q * BATCH + b) * DMOD + h * DHEAD + dh] = __float2bfloat16(o / l);
  }
}

// ---------------- LayerNorm(a + r) * g + be -> outf/outb ----------------
__global__ __launch_bounds__(256) void ln_kernel(const float* __restrict__ a,
    const float* __restrict__ r, const float* __restrict__ g,
    const float* __restrict__ be, float* __restrict__ outf, bf16* __restrict__ outb) {
  int m = blockIdx.x;
  int tid = threadIdx.x;
  float vals[4];
  float s1 = 0.f, s2 = 0.f;
  for (int j = 0; j < 4; j++) {
    int d = tid + j * 256;
    float v = a[(size_t)m * DMOD + d] + r[(size_t)m * DMOD + d];
    vals[j] = v; s1 += v; s2 += v * v;
  }
  __shared__ float red[8];
  for (int d = 1; d < 64; d <<= 1) { s1 += __shfl_xor(s1, d); s2 += __shfl_xor(s2, d); }
  int w = tid >> 6, lane = tid & 63;
  if (lane == 0) { red[w] = s1; red[4 + w] = s2; }
  __syncthreads();
  s1 = red[0] + red[1] + red[2] + red[3];
  s2 = red[4] + red[5] + red[6] + red[7];
  float mean = s1 * (1.0f / DMOD);
  float var = s2 * (1.0f / DMOD) - mean * mean;
  float rstd = rsqrtf(var + 1e-5f);
  for (int j = 0; j < 4; j++) {
    int d = tid + j * 256;
    float o = (vals[j] - mean) * rstd * g[d] + be[d];
    outf[(size_t)m * DMOD + d] = o;
    outb[(size_t)m * DMOD + d] = __float2bfloat16(o);
  }
}

// ---------------- head ----------------
__global__ __launch_bounds__(256) void head_kernel(const float* __restrict__ x,
    const float* __restrict__ Wh, const float* __restrict__ bh, float* __restrict__ out) {
  int m = blockIdx.x * 4 + (threadIdx.x >> 6);
  int lane = threadIdx.x & 63;
  float s = 0.f;
  for (int j = 0; j < 16; j++) {
    int d = lane + j * 64;
    s += x[(size_t)m * DMOD + d] * Wh[d];
  }
  for (int d = 1; d < 64; d <<= 1) s += __shfl_xor(s, d);
  if (lane == 0) out[m] = s + bh[0];
}

extern "C" void kernel_launch(void* const* d_in, const int* in_sizes, int n_in,
                              void* d_out, int out_size, void* d_ws, size_t ws_size,
                              hipStream_t stream) {
  (void)in_sizes; (void)n_in; (void)out_size; (void)ws_size;
  const float* tokens = (const float*)d_in[0];
  const float* Win    = (const float*)d_in[1];
  const float* binp   = (const float*)d_in[2];
  const float* pos    = (const float*)d_in[3];
  const float* Wq     = (const float*)d_in[4];
  const float* bq     = (const float*)d_in[5];
  const float* Wk     = (const float*)d_in[6];
  const float* bk     = (const float*)d_in[7];
  const float* Wv     = (const float*)d_in[8];
  const float* bv     = (const float*)d_in[9];
  const float* Wo     = (const float*)d_in[10];
  const float* bo     = (const float*)d_in[11];
  const float* W1     = (const float*)d_in[12];
  const float* b1     = (const float*)d_in[13];
  const float* W2     = (const float*)d_in[14];
  const float* b2     = (const float*)d_in[15];
  const float* g1     = (const float*)d_in[16];
  const float* be1    = (const float*)d_in[17];
  const float* g2     = (const float*)d_in[18];
  const float* be2    = (const float*)d_in[19];
  const float* Wh     = (const float*)d_in[20];
  const float* bhp    = (const float*)d_in[21];
  float* out = (float*)d_out;

  char* p = (char*)d_ws;
  auto alloc = [&](size_t bytes) { char* r = p; p += (bytes + 255) & ~(size_t)255; return r; };
  float* xf   = (float*)alloc((size_t)MROWS * DMOD * 4);
  bf16*  xb   = (bf16*) alloc((size_t)MROWS * DMOD * 2);
  float* x2f  = (float*)alloc((size_t)MROWS * DMOD * 4);
  bf16*  x2b  = (bf16*) alloc((size_t)MROWS * DMOD * 2);
  float* tmpf = (float*)alloc((size_t)MROWS * DMOD * 4);
  bf16*  qb   = (bf16*) alloc((size_t)MROWS * DMOD * 2);
  bf16*  kb   = (bf16*) alloc((size_t)MROWS * DMOD * 2);
  bf16*  vt   = (bf16*) alloc((size_t)MROWS * DMOD * 2);
  bf16*  ob   = (bf16*) alloc((size_t)MROWS * DMOD * 2);
  bf16*  hb   = (bf16*) alloc((size_t)MROWS * FDIM * 2);
  bf16*  wb   = (bf16*) alloc((4 * DD_ + 2 * FD_) * 2);   // 16 MB per-layer weights
  float* WinT = (float*)alloc((size_t)TDIM * DMOD * 4);
  float2* rope2 = (float2*)alloc((size_t)S_LEN * 32 * 8);
  float* pO   = (float*)alloc((size_t)32 * 64 * 4 * 1024 * 4);  // 33.5 MB partial O
  float* pML  = (float*)alloc((size_t)32 * 64 * 4 * 32 * 4);    // 1 MB partial m/l

  transpose_win<<<(TDIM * DMOD + 255) / 256, 256, 0, stream>>>(Win, WinT);
  rope_table<<<(S_LEN * 32 + 255) / 256, 256, 0, stream>>>(rope2);
  embed_kernel<<<dim3(MROWS, 4), 256, 0, stream>>>(tokens, WinT, binp, pos, xf, xb);

  const int nW4 = (int)((4 * DD_ + 2 * FD_) / 4);

  for (int l = 0; l < NLAYER; l++) {
    f2b_layer<<<(nW4 + 255) / 256, 256, 0, stream>>>(
        (const float4*)(Wq + l * DD_), (const float4*)(Wk + l * DD_),
        (const float4*)(Wv + l * DD_), (const float4*)(Wo + l * DD_),
        (const float4*)(W1 + l * FD_), (const float4*)(W2 + l * FD_), (ushort4*)wb);

    gemm128<128, 0><<<dim3(3 * DMOD / 128, MROWS / 128), 256, 0, stream>>>(
        xb, wb, bq + l * DMOD, bk + l * DMOD, bv + l * DMOD, rope2,
        nullptr, qb, kb, vt, 3 * DMOD, DMOD);

    flash_part<<<dim3(40, BATCH * NHEAD), 256, 0, stream>>>(qb, kb, vt, pO, pML);
    flash_merge<<<dim3(S_LEN / 16, BATCH * NHEAD), 256, 0, stream>>>(pO, pML, ob);

    gemm128<64, 1><<<dim3(DMOD / 64, MROWS / 128), 256, 0, stream>>>(
        ob, wb + 3 * DD_, bo + l * DMOD, nullptr, nullptr, nullptr,
        tmpf, nullptr, nullptr, nullptr, DMOD, DMOD);

    ln_kernel<<<MROWS, 256, 0, stream>>>(xf, tmpf, g1 + l * DMOD, be1 + l * DMOD, x2f, x2b);

    gemm128<128, 2><<<dim3(FDIM / 128, MROWS / 128), 256, 0, stream>>>(
        x2b, wb + 4 * DD_, b1 + l * FDIM, nullptr, nullptr, nullptr,
        nullptr, hb, nullptr, nullptr, FDIM, DMOD);

    gemm128<64, 1><<<dim3(DMOD / 64, MROWS / 128), 256, 0, stream>>>(
        hb, wb + 4 * DD_ + FD_, b2 + l * DMOD, nullptr, nullptr, nullptr,
        tmpf, nullptr, nullptr, nullptr, DMOD, FDIM);

    ln_kernel<<<MROWS, 256, 0, stream>>>(x2f, tmpf, g2 + l * DMOD, be2 + l * DMOD, xf, xb);
  }

  head_kernel<<<MROWS / 4, 256, 0, stream>>>(xf, Wh, bhp, out);
}

// Round 4
// 1639.896 us; speedup vs baseline: 1.0457x; 1.0457x over previous
//
#include <hip/hip_runtime.h>
#include <hip/hip_bf16.h>

typedef __hip_bfloat16 bf16;
typedef float f32x4 __attribute__((ext_vector_type(4)));
typedef short s16x8 __attribute__((ext_vector_type(8)));
typedef int i32x4 __attribute__((ext_vector_type(4)));

#define S_LEN 1024
#define BATCH 2
#define TDIM 138
#define KPAD 160
#define DMOD 1024
#define NHEAD 16
#define DHEAD 64
#define NLAYER 8
#define FDIM 2048
#define MROWS 2048
static const size_t DD_ = (size_t)DMOD * DMOD;   // 1M elems
static const size_t FD_ = (size_t)FDIM * DMOD;   // 2M elems

__device__ __forceinline__ void load_lds16(const bf16* g, bf16* l) {
  __builtin_amdgcn_global_load_lds((const __attribute__((address_space(1))) void*)g,
                                   (__attribute__((address_space(3))) void*)l, 16, 0, 0);
}

__device__ __forceinline__ unsigned pack2(float a, float b) {
  unsigned x = __builtin_bit_cast(unsigned short, __float2bfloat16(a));
  unsigned y = __builtin_bit_cast(unsigned short, __float2bfloat16(b));
  return x | (y << 16);
}

// ---------------- per-layer weight f32 -> bf16 convert ----------------
__global__ __launch_bounds__(256) void f2b_layer(
    const float4* __restrict__ Wq, const float4* __restrict__ Wk,
    const float4* __restrict__ Wv, const float4* __restrict__ Wo,
    const float4* __restrict__ W1, const float4* __restrict__ W2,
    ushort4* __restrict__ dst) {
  int i = blockIdx.x * 256 + threadIdx.x;
  const int DD4 = (int)(DD_ / 4), FD4 = (int)(FD_ / 4);
  if (i >= 4 * DD4 + 2 * FD4) return;
  const float4* src; int off;
  if (i < 3 * DD4) { int w = i / DD4; off = i - w * DD4; src = w == 0 ? Wq : (w == 1 ? Wk : Wv); }
  else if (i < 4 * DD4) { src = Wo; off = i - 3 * DD4; }
  else if (i < 4 * DD4 + FD4) { src = W1; off = i - 4 * DD4; }
  else { src = W2; off = i - 4 * DD4 - FD4; }
  float4 v = src[off];
  ushort4 o;
  o.x = __builtin_bit_cast(unsigned short, __float2bfloat16(v.x));
  o.y = __builtin_bit_cast(unsigned short, __float2bfloat16(v.y));
  o.z = __builtin_bit_cast(unsigned short, __float2bfloat16(v.z));
  o.w = __builtin_bit_cast(unsigned short, __float2bfloat16(v.w));
  dst[i] = o;
}

// ---------------- pad+convert a row-major f32 [R][TDIM] -> bf16 [R][KPAD] ----------------
__global__ __launch_bounds__(256) void pad_cvt(const float* __restrict__ in,
                                               bf16* __restrict__ out, int R) {
  int i = blockIdx.x * 256 + threadIdx.x;
  if (i >= R * KPAD) return;
  int r = i / KPAD, t = i - r * KPAD;
  out[i] = __float2bfloat16(t < TDIM ? in[r * TDIM + t] : 0.0f);
}

// ---------------- rope table ----------------
__global__ __launch_bounds__(256) void rope_table(float2* __restrict__ t) {
  int idx = blockIdx.x * 256 + threadIdx.x;
  if (idx >= S_LEN * 32) return;
  int s = idx >> 5, i = idx & 31;
  float freq = __expf(-(float)i * (2.0f / (float)DHEAD) * 9.210340371976184f);
  float sn, cs;
  sincosf((float)s * freq, &sn, &cs);
  t[idx] = make_float2(cs, sn);
}

// ---------------- 128-tile NT GEMM (m97 structure), 1D grid + XCD swizzle ----------------
// EPI 0: fused QKV (rope Q/K head-layout, V^T). EPI 1: f32 + bias. EPI 2: relu bf16.
// EPI 3: embed (bias + pos table, f32 + bf16 outputs).
template<int TN, int EPI>
__global__ __launch_bounds__(256) void gemm128(
    const bf16* __restrict__ A, const bf16* __restrict__ W,
    const float* __restrict__ b0p, const float* __restrict__ b1p, const float* __restrict__ b2p,
    const float2* __restrict__ rope2, float* __restrict__ Cf,
    bf16* __restrict__ Cb0, bf16* __restrict__ Cb1, bf16* __restrict__ Cb2,
    int N, int K, int nbx) {
  constexpr int NJ = TN / 32;
  __shared__ bf16 As[128 * 32];
  __shared__ bf16 Bs[TN * 32];
  int nwg = gridDim.x, bid = blockIdx.x;
  int wg = (bid & 7) * (nwg >> 3) + (bid >> 3);   // XCD-contiguous chunks
  int bx = wg % nbx, by = wg / nbx;
  int bn = bx * TN, bm = by * 128;
  int tid = threadIdx.x, lane = tid & 63, w = tid >> 6;
  int lo = lane & 15, hi = lane >> 4;
  int wr = (w >> 1) * 64, wc = (w & 1) * (TN / 2);
  f32x4 acc[4][NJ] = {};

  int srow = tid >> 2, sseg = tid & 3;
  const bf16* gA = A + (size_t)(bm + srow) * K + sseg * 8;
  const bf16* gB = W + (size_t)(bn + srow) * K + sseg * 8;
  bf16* lA = As + srow * 32 + sseg * 8;
  bf16* lB = Bs + srow * 32 + sseg * 8;

  for (int k0 = 0; k0 < K; k0 += 32) {
    load_lds16(gA + k0, lA);
    load_lds16(gA + (size_t)64 * K + k0, lA + 64 * 32);
    load_lds16(gB + k0, lB);
    if constexpr (TN == 128) load_lds16(gB + (size_t)64 * K + k0, lB + 64 * 32);
    __syncthreads();
    s16x8 af[4], bfr[NJ];
#pragma unroll
    for (int mi = 0; mi < 4; mi++) af[mi] = *(const s16x8*)(As + (wr + mi * 16 + lo) * 32 + hi * 8);
#pragma unroll
    for (int nj = 0; nj < NJ; nj++) bfr[nj] = *(const s16x8*)(Bs + (wc + nj * 16 + lo) * 32 + hi * 8);
#pragma unroll
    for (int mi = 0; mi < 4; mi++)
#pragma unroll
      for (int nj = 0; nj < NJ; nj++)
        acc[mi][nj] = __builtin_amdgcn_mfma_f32_16x16x32_bf16(af[mi], bfr[nj], acc[mi][nj], 0, 0, 0);
    __syncthreads();
  }

#pragma unroll
  for (int mi = 0; mi < 4; mi++)
#pragma unroll
    for (int nj = 0; nj < NJ; nj++)
#pragma unroll
      for (int r = 0; r < 4; r++) {
        int m = bm + wr + mi * 16 + hi * 4 + r;
        int n = bn + wc + nj * 16 + lo;
        float v = acc[mi][nj][r];
        if constexpr (EPI == 0) {
          int which = n >> 10;
          int d = n & 1023, h = d >> 6, dh = d & 63;
          int s = m >> 1, bb = m & 1;
          const float* bp = which == 0 ? b0p : (which == 1 ? b1p : b2p);
          v += bp[d];
          if (which < 2) {
            float pv = __shfl_xor(v, 1);
            float2 cn = rope2[s * 32 + (dh >> 1)];
            float o = (dh & 1) ? (v * cn.x + pv * cn.y) : (v * cn.x - pv * cn.y);
            bf16* dst = which == 0 ? Cb0 : Cb1;
            dst[(((size_t)(bb * NHEAD + h)) * S_LEN + s) * DHEAD + dh] = __float2bfloat16(o);
          } else {
            Cb2[(((size_t)(bb * NHEAD + h)) * DHEAD + dh) * S_LEN + s] = __float2bfloat16(v);
          }
        } else if constexpr (EPI == 1) {
          Cf[(size_t)m * N + n] = v + b0p[n];
        } else if constexpr (EPI == 2) {
          Cb0[(size_t)m * N + n] = __float2bfloat16(fmaxf(v + b0p[n], 0.0f));
        } else {
          float v2 = v + b0p[n] + b1p[(size_t)(m >> 1) * DMOD + n];
          Cf[(size_t)m * N + n] = v2;
          Cb0[(size_t)m * N + n] = __float2bfloat16(v2);
        }
      }
}

// ---------------- split-K flash attention, part 1 (register-pipelined) ----------------
__global__ __launch_bounds__(256) void flash_part(const bf16* __restrict__ Q,
    const bf16* __restrict__ K, const bf16* __restrict__ Vt,
    float* __restrict__ pO, float* __restrict__ pML) {
  int bh = blockIdx.y;
  int w = threadIdx.x >> 6, lane = threadIdx.x & 63;
  int lo = lane & 15, hi = lane >> 4;
  int widx = blockIdx.x * 4 + w;           // 0..159
  int ch, qt;
  if (widx < 64)       { ch = 0; qt = widx; }
  else if (widx < 112) { ch = 1; qt = 16 + widx - 64; }
  else if (widx < 144) { ch = 2; qt = 32 + widx - 112; }
  else                 { ch = 3; qt = 48 + widx - 144; }
  int q0 = qt * 16, qa = q0 + lo;
  int kc0 = ch * 256;
  int kend = min(kc0 + 256, q0 + 16);
  int nkt = (kend - kc0 + 31) >> 5;

  const size_t qkb = (size_t)bh * S_LEN * DHEAD;
  const bf16* qp = Q + qkb + (size_t)qa * DHEAD + hi * 8;
  s16x8 bq0 = *(const s16x8*)qp;
  s16x8 bq1 = *(const s16x8*)(qp + 32);
  const bf16* kB = K + qkb;
  const bf16* vB = Vt + qkb;
  f32x4 accO[4] = {};
  float mv = -INFINITY, lv = 0.0f;
  const float SC = 0.18033688011112042f;   // (1/8) * log2(e)

  auto loadTile = [&](int kc, s16x8& k0, s16x8& k1, s16x8& k2, s16x8& k3,
                      s16x8& v0, s16x8& v1, s16x8& v2, s16x8& v3) {
    const bf16* kp = kB + (size_t)(kc + lo) * DHEAD + hi * 8;
    k0 = *(const s16x8*)kp;
    k1 = *(const s16x8*)(kp + 32);
    k2 = *(const s16x8*)(kp + 16 * DHEAD);
    k3 = *(const s16x8*)(kp + 16 * DHEAD + 32);
    const bf16* vp = vB + (size_t)lo * S_LEN + kc + hi * 8;
    v0 = *(const s16x8*)vp;
    v1 = *(const s16x8*)(vp + (size_t)16 * S_LEN);
    v2 = *(const s16x8*)(vp + (size_t)32 * S_LEN);
    v3 = *(const s16x8*)(vp + (size_t)48 * S_LEN);
  };

  auto compute = [&](int kc, s16x8 k0, s16x8 k1, s16x8 k2, s16x8 k3,
                     s16x8 v0, s16x8 v1, s16x8 v2, s16x8 v3) {
    f32x4 st0 = {}, st1 = {};
    st0 = __builtin_amdgcn_mfma_f32_16x16x32_bf16(k0, bq0, st0, 0, 0, 0);
    st0 = __builtin_amdgcn_mfma_f32_16x16x32_bf16(k1, bq1, st0, 0, 0, 0);
    st1 = __builtin_amdgcn_mfma_f32_16x16x32_bf16(k2, bq0, st1, 0, 0, 0);
    st1 = __builtin_amdgcn_mfma_f32_16x16x32_bf16(k3, bq1, st1, 0, 0, 0);
    float p[8], pmax = -INFINITY;
    if (kc + 31 > q0) {          // diagonal tile: causal mask (wave-uniform branch)
#pragma unroll
      for (int r = 0; r < 4; r++) {
        int k0a = kc + hi * 4 + r;
        float s0 = (k0a <= qa) ? st0[r] * SC : -INFINITY;
        float s1 = (k0a + 16 <= qa) ? st1[r] * SC : -INFINITY;
        p[r] = s0; p[4 + r] = s1;
        pmax = fmaxf(pmax, fmaxf(s0, s1));
      }
    } else {
#pragma unroll
      for (int r = 0; r < 4; r++) {
        float s0 = st0[r] * SC, s1 = st1[r] * SC;
        p[r] = s0; p[4 + r] = s1;
        pmax = fmaxf(pmax, fmaxf(s0, s1));
      }
    }
    pmax = fmaxf(pmax, __shfl_xor(pmax, 16));
    pmax = fmaxf(pmax, __shfl_xor(pmax, 32));
    float mnew = fmaxf(mv, pmax);
    float fs = exp2f(mv - mnew);
    float sum = 0.0f;
#pragma unroll
    for (int j = 0; j < 8; j++) { p[j] = exp2f(p[j] - mnew); sum += p[j]; }
    sum += __shfl_xor(sum, 16);
    sum += __shfl_xor(sum, 32);
    lv = lv * fs + sum;
    mv = mnew;
#pragma unroll
    for (int c = 0; c < 4; c++) accO[c] *= fs;
    unsigned u0 = pack2(p[0], p[1]), u1 = pack2(p[2], p[3]);
    unsigned u2 = pack2(p[4], p[5]), u3 = pack2(p[6], p[7]);
    int s1l = lo + ((hi & 1) << 5);
    int s2l = s1l + 16;
    unsigned a0 = (unsigned)__shfl((int)u0, s1l), a1 = (unsigned)__shfl((int)u1, s1l);
    unsigned a2 = (unsigned)__shfl((int)u0, s2l), a3 = (unsigned)__shfl((int)u1, s2l);
    unsigned c0 = (unsigned)__shfl((int)u2, s1l), c1 = (unsigned)__shfl((int)u3, s1l);
    unsigned c2 = (unsigned)__shfl((int)u2, s2l), c3 = (unsigned)__shfl((int)u3, s2l);
    bool lk = hi < 2;
    i32x4 pi;
    pi.x = (int)(lk ? a0 : c0); pi.y = (int)(lk ? a1 : c1);
    pi.z = (int)(lk ? a2 : c2); pi.w = (int)(lk ? a3 : c3);
    s16x8 pf = __builtin_bit_cast(s16x8, pi);
    accO[0] = __builtin_amdgcn_mfma_f32_16x16x32_bf16(v0, pf, accO[0], 0, 0, 0);
    accO[1] = __builtin_amdgcn_mfma_f32_16x16x32_bf16(v1, pf, accO[1], 0, 0, 0);
    accO[2] = __builtin_amdgcn_mfma_f32_16x16x32_bf16(v2, pf, accO[2], 0, 0, 0);
    accO[3] = __builtin_amdgcn_mfma_f32_16x16x32_bf16(v3, pf, accO[3], 0, 0, 0);
  };

  // register double-buffer: named sets, unroll-2 rotation (static indexing)
  s16x8 A0, A1, A2, A3, A4, A5, A6, A7;
  s16x8 B0, B1, B2, B3, B4, B5, B6, B7;
  loadTile(kc0, A0, A1, A2, A3, A4, A5, A6, A7);
  for (int kt = 0; kt < nkt; kt += 2) {
    if (kt + 1 < nkt) loadTile(kc0 + (kt + 1) * 32, B0, B1, B2, B3, B4, B5, B6, B7);
    compute(kc0 + kt * 32, A0, A1, A2, A3, A4, A5, A6, A7);
    if (kt + 1 < nkt) {
      if (kt + 2 < nkt) loadTile(kc0 + (kt + 2) * 32, A0, A1, A2, A3, A4, A5, A6, A7);
      compute(kc0 + (kt + 1) * 32, B0, B1, B2, B3, B4, B5, B6, B7);
    }
  }

  int pbase = (bh * 64 + qt) * 4 + ch;
  float* po = pO + (size_t)pbase * 1024 + lo * 64 + hi * 4;
#pragma unroll
  for (int c = 0; c < 4; c++) *(f32x4*)(po + c * 16) = accO[c];
  if (hi == 0) {
    pML[pbase * 32 + lo] = mv;
    pML[pbase * 32 + 16 + lo] = lv;
  }
}

// ---------------- split-K flash attention, merge ----------------
__global__ __launch_bounds__(256) void flash_merge(const float* __restrict__ pO,
    const float* __restrict__ pML, bf16* __restrict__ O) {
  int qt = blockIdx.x, bh = blockIdx.y;
  int b = bh >> 4, h = bh & 15;
  int nch = (qt >> 4) + 1;
  int t = threadIdx.x;
  int dh = t & 63, r0 = t >> 6;
  int pb0 = (bh * 64 + qt) * 4;
#pragma unroll
  for (int j = 0; j < 4; j++) {
    int row = r0 + j * 4;
    float ms = -INFINITY;
    for (int i = 0; i < nch; i++) ms = fmaxf(ms, pML[(pb0 + i) * 32 + row]);
    float l = 0.0f, o = 0.0f;
    for (int i = 0; i < nch; i++) {
      float wgt = exp2f(pML[(pb0 + i) * 32 + row] - ms);
      l += wgt * pML[(pb0 + i) * 32 + 16 + row];
      o += wgt * pO[(size_t)(pb0 + i) * 1024 + row * 64 + dh];
    }
    int q = qt * 16 + row;
    O[((size_t)q * BATCH + b) * DMOD + h * DHEAD + dh] = __float2bfloat16(o / l);
  }
}

// ---------------- LayerNorm(a + r) * g + be -> outf/outb ----------------
__global__ __launch_bounds__(256) void ln_kernel(const float* __restrict__ a,
    const float* __restrict__ r, const float* __restrict__ g,
    const float* __restrict__ be, float* __restrict__ outf, bf16* __restrict__ outb) {
  int m = blockIdx.x;
  int tid = threadIdx.x;
  float vals[4];
  float s1 = 0.f, s2 = 0.f;
  for (int j = 0; j < 4; j++) {
    int d = tid + j * 256;
    float v = a[(size_t)m * DMOD + d] + r[(size_t)m * DMOD + d];
    vals[j] = v; s1 += v; s2 += v * v;
  }
  __shared__ float red[8];
  for (int d = 1; d < 64; d <<= 1) { s1 += __shfl_xor(s1, d); s2 += __shfl_xor(s2, d); }
  int w = tid >> 6, lane = tid & 63;
  if (lane == 0) { red[w] = s1; red[4 + w] = s2; }
  __syncthreads();
  s1 = red[0] + red[1] + red[2] + red[3];
  s2 = red[4] + red[5] + red[6] + red[7];
  float mean = s1 * (1.0f / DMOD);
  float var = s2 * (1.0f / DMOD) - mean * mean;
  float rstd = rsqrtf(var + 1e-5f);
  for (int j = 0; j < 4; j++) {
    int d = tid + j * 256;
    float o = (vals[j] - mean) * rstd * g[d] + be[d];
    outf[(size_t)m * DMOD + d] = o;
    outb[(size_t)m * DMOD + d] = __float2bfloat16(o);
  }
}

// ---------------- head ----------------
__global__ __launch_bounds__(256) void head_kernel(const float* __restrict__ x,
    const float* __restrict__ Wh, const float* __restrict__ bh, float* __restrict__ out) {
  int m = blockIdx.x * 4 + (threadIdx.x >> 6);
  int lane = threadIdx.x & 63;
  float s = 0.f;
  for (int j = 0; j < 16; j++) {
    int d = lane + j * 64;
    s += x[(size_t)m * DMOD + d] * Wh[d];
  }
  for (int d = 1; d < 64; d <<= 1) s += __shfl_xor(s, d);
  if (lane == 0) out[m] = s + bh[0];
}

extern "C" void kernel_launch(void* const* d_in, const int* in_sizes, int n_in,
                              void* d_out, int out_size, void* d_ws, size_t ws_size,
                              hipStream_t stream) {
  (void)in_sizes; (void)n_in; (void)out_size; (void)ws_size;
  const float* tokens = (const float*)d_in[0];
  const float* Win    = (const float*)d_in[1];
  const float* binp   = (const float*)d_in[2];
  const float* pos    = (const float*)d_in[3];
  const float* Wq     = (const float*)d_in[4];
  const float* bq     = (const float*)d_in[5];
  const float* Wk     = (const float*)d_in[6];
  const float* bk     = (const float*)d_in[7];
  const float* Wv     = (const float*)d_in[8];
  const float* bv     = (const float*)d_in[9];
  const float* Wo     = (const float*)d_in[10];
  const float* bo     = (const float*)d_in[11];
  const float* W1     = (const float*)d_in[12];
  const float* b1     = (const float*)d_in[13];
  const float* W2     = (const float*)d_in[14];
  const float* b2     = (const float*)d_in[15];
  const float* g1     = (const float*)d_in[16];
  const float* be1    = (const float*)d_in[17];
  const float* g2     = (const float*)d_in[18];
  const float* be2    = (const float*)d_in[19];
  const float* Wh     = (const float*)d_in[20];
  const float* bhp    = (const float*)d_in[21];
  float* out = (float*)d_out;

  char* p = (char*)d_ws;
  auto alloc = [&](size_t bytes) { char* r = p; p += (bytes + 255) & ~(size_t)255; return r; };
  float* xf   = (float*)alloc((size_t)MROWS * DMOD * 4);
  bf16*  xb   = (bf16*) alloc((size_t)MROWS * DMOD * 2);
  float* x2f  = (float*)alloc((size_t)MROWS * DMOD * 4);
  bf16*  x2b  = (bf16*) alloc((size_t)MROWS * DMOD * 2);
  float* tmpf = (float*)alloc((size_t)MROWS * DMOD * 4);
  bf16*  qb   = (bf16*) alloc((size_t)MROWS * DMOD * 2);
  bf16*  kb   = (bf16*) alloc((size_t)MROWS * DMOD * 2);
  bf16*  vt   = (bf16*) alloc((size_t)MROWS * DMOD * 2);
  bf16*  ob   = (bf16*) alloc((size_t)MROWS * DMOD * 2);
  bf16*  hb   = (bf16*) alloc((size_t)MROWS * FDIM * 2);
  bf16*  wb   = (bf16*) alloc((4 * DD_ + 2 * FD_) * 2);   // 16 MB per-layer weights
  bf16*  tokb = (bf16*) alloc((size_t)MROWS * KPAD * 2);
  bf16*  winb = (bf16*) alloc((size_t)DMOD * KPAD * 2);
  float2* rope2 = (float2*)alloc((size_t)S_LEN * 32 * 8);
  float* pO   = (float*)alloc((size_t)32 * 64 * 4 * 1024 * 4);  // 33.5 MB partial O
  float* pML  = (float*)alloc((size_t)32 * 64 * 4 * 32 * 4);    // 1 MB partial m/l

  rope_table<<<(S_LEN * 32 + 255) / 256, 256, 0, stream>>>(rope2);
  pad_cvt<<<(MROWS * KPAD + 255) / 256, 256, 0, stream>>>(tokens, tokb, MROWS);
  pad_cvt<<<(DMOD * KPAD + 255) / 256, 256, 0, stream>>>(Win, winb, DMOD);
  // embed GEMM: x = tokens @ Win^T + bin + pos  (M=2048, N=1024, K=160)
  gemm128<128, 3><<<128, 256, 0, stream>>>(
      tokb, winb, binp, pos, nullptr, nullptr,
      xf, xb, nullptr, nullptr, DMOD, KPAD, 8);

  const int nW4 = (int)((4 * DD_ + 2 * FD_) / 4);

  for (int l = 0; l < NLAYER; l++) {
    f2b_layer<<<(nW4 + 255) / 256, 256, 0, stream>>>(
        (const float4*)(Wq + l * DD_), (const float4*)(Wk + l * DD_),
        (const float4*)(Wv + l * DD_), (const float4*)(Wo + l * DD_),
        (const float4*)(W1 + l * FD_), (const float4*)(W2 + l * FD_), (ushort4*)wb);

    gemm128<128, 0><<<384, 256, 0, stream>>>(
        xb, wb, bq + l * DMOD, bk + l * DMOD, bv + l * DMOD, rope2,
        nullptr, qb, kb, vt, 3 * DMOD, DMOD, 24);

    flash_part<<<dim3(40, BATCH * NHEAD), 256, 0, stream>>>(qb, kb, vt, pO, pML);
    flash_merge<<<dim3(S_LEN / 16, BATCH * NHEAD), 256, 0, stream>>>(pO, pML, ob);

    gemm128<64, 1><<<256, 256, 0, stream>>>(
        ob, wb + 3 * DD_, bo + l * DMOD, nullptr, nullptr, nullptr,
        tmpf, nullptr, nullptr, nullptr, DMOD, DMOD, 16);

    ln_kernel<<<MROWS, 256, 0, stream>>>(xf, tmpf, g1 + l * DMOD, be1 + l * DMOD, x2f, x2b);

    gemm128<128, 2><<<256, 256, 0, stream>>>(
        x2b, wb + 4 * DD_, b1 + l * FDIM, nullptr, nullptr, nullptr,
        nullptr, hb, nullptr, nullptr, FDIM, DMOD, 16);

    gemm128<64, 1><<<256, 256, 0, stream>>>(
        hb, wb + 4 * DD_ + FD_, b2 + l * DMOD, nullptr, nullptr, nullptr,
        tmpf, nullptr, nullptr, nullptr, DMOD, FDIM, 16);

    ln_kernel<<<MROWS, 256, 0, stream>>>(x2f, tmpf, g2 + l * DMOD, be2 + l * DMOD, xf, xb);
  }

  head_kernel<<<MROWS / 4, 256, 0, stream>>>(xf, Wh, bhp, out);
}